// Round 1
// baseline (507.984 us; speedup 1.0000x reference)
//
#include <hip/hip_runtime.h>
#include <hip/hip_bf16.h>
#include <float.h>

#define K_NEI 9
#define M 4096
#define N 65536
#define D 128
#define SEGS 32
#define SEG_LEN (N / SEGS)     // 2048 bank rows per segment
#define QB 128                 // queries per block
#define BB 64                  // bank rows per chunk
#define CHUNKS (SEG_LEN / BB)  // 32
#define QGROUPS (M / QB)       // 32
// events at ch = 0,1,2,3,5,7,11,15,19,23
#define EV_MASK 0x8888AFu

typedef __bf16 bf16x8 __attribute__((ext_vector_type(8)));
typedef float floatx4 __attribute__((ext_vector_type(4)));

static __device__ inline floatx4 mfma16(bf16x8 a, bf16x8 b, floatx4 c) {
    return __builtin_amdgcn_mfma_f32_16x16x32_bf16(a, b, c, 0, 0, 0);
}

// async global->LDS, 16B per lane, dest = lds_base + lane*16
#define GL_LDS16(gp, lp)                                                     \
    __builtin_amdgcn_global_load_lds(                                        \
        (const __attribute__((address_space(1))) unsigned int*)(const void*)(gp), \
        (__attribute__((address_space(3))) unsigned int*)(void*)(lp), 16, 0, 0)

// ---- sorted-9 toolkit -----------------------------------------------------
static __device__ inline void ce(float& a, float& b) {
    float lo = fminf(a, b), hi = fmaxf(a, b); a = lo; b = hi;
}
// canonical optimal 25-CE / depth-7 sorting network for 9 (ascending)
static __device__ inline void sort9(float t[K_NEI]) {
    ce(t[0],t[3]); ce(t[1],t[7]); ce(t[2],t[5]); ce(t[4],t[8]);
    ce(t[0],t[7]); ce(t[2],t[4]); ce(t[3],t[8]); ce(t[5],t[6]);
    ce(t[0],t[2]); ce(t[1],t[3]); ce(t[4],t[5]); ce(t[7],t[8]);
    ce(t[1],t[4]); ce(t[3],t[6]); ce(t[5],t[7]);
    ce(t[0],t[1]); ce(t[2],t[4]); ce(t[3],t[5]); ce(t[6],t[8]);
    ce(t[2],t[3]); ce(t[4],t[5]); ce(t[6],t[7]);
    ce(t[1],t[2]); ce(t[3],t[4]); ce(t[5],t[6]);
}
// t, o sorted ascending -> t = sorted 9 smallest of union (bitonic min trick)
static __device__ inline void merge9(float t[K_NEI], const float o[K_NEI]) {
    float m[K_NEI];
#pragma unroll
    for (int i = 0; i < K_NEI; ++i) m[i] = fminf(t[i], o[K_NEI - 1 - i]);
    sort9(m);
#pragma unroll
    for (int i = 0; i < K_NEI; ++i) t[i] = m[i];
}
// pool the 4 partner lanes (lane ^16, ^32): all 4 end with identical exact
// top-9 of the quad's union. ONLY valid if the 4 lists are element-disjoint.
static __device__ inline void quad_merge(float t[K_NEI]) {
    float o[K_NEI];
#pragma unroll
    for (int i = 0; i < K_NEI; ++i) o[i] = __shfl_xor(t[i], 16, 64);
    merge9(t, o);
#pragma unroll
    for (int i = 0; i < K_NEI; ++i) o[i] = __shfl_xor(t[i], 32, 64);
    merge9(t, o);
}

// ---------------------------------------------------------------------------
// Kernel 1 (fused prep): fp32 -> bf16 convert + row norms for BOTH inputs,
// plus per-call init of thr_g (gates) and done (qgroup counters).
// Vectorized: 32 lanes/row, float4 loads, packed 4B bf16 stores.
// ---------------------------------------------------------------------------
static __device__ inline unsigned pack2bf(float a, float b) {
    __hip_bfloat16 x = __float2bfloat16(a), y = __float2bfloat16(b);
    unsigned short ux = *(unsigned short*)&x, uy = *(unsigned short*)&y;
    return (unsigned)ux | ((unsigned)uy << 16);
}

__global__ void prep_kernel(const float* __restrict__ bank,
                            const float* __restrict__ feats,
                            __hip_bfloat16* __restrict__ bankbf,
                            __hip_bfloat16* __restrict__ featbf,
                            float* __restrict__ bsqn,
                            float* __restrict__ qsq,
                            int* __restrict__ thr_g,
                            int* __restrict__ done) {
    int row = (int)((blockIdx.x * blockDim.x + threadIdx.x) >> 5);
    int l   = threadIdx.x & 31;
    if (row >= N + M) return;
    const float* src = (row < N) ? (bank + (size_t)row * D)
                                 : (feats + (size_t)(row - N) * D);
    __hip_bfloat16* dst = (row < N) ? (bankbf + (size_t)row * D)
                                    : (featbf + (size_t)(row - N) * D);
    float4 v = ((const float4*)src)[l];
    float s = v.x * v.x + v.y * v.y + v.z * v.z + v.w * v.w;
    uint2 p;
    p.x = pack2bf(v.x, v.y);
    p.y = pack2bf(v.z, v.w);
    ((uint2*)dst)[l] = p;
    // xor-reduce within the 32-lane group (offsets <32 never cross groups)
#pragma unroll
    for (int off = 16; off > 0; off >>= 1) s += __shfl_xor(s, off, 64);
    if (l == 0) {
        if (row < N) {
            bsqn[row] = -0.5f * s;
        } else {
            qsq[row - N] = s;
            thr_g[row - N] = 0x7f7f7f7f;   // 3.39e38f
        }
    }
    if (l == 1 && row >= N && row < N + QGROUPS) done[row - N] = 0;
}

// ---------------------------------------------------------------------------
// Kernel 2: MFMA distance GEMM + fused per-query top-9 + fused final merge.
// grid = 1024 blocks (targets 3 blocks/CU via launch_bounds(256,3) + 37KB
// LDS) of 256 threads (4 waves); XCD-swizzled: seg%8 == blockIdx%8.
//
// acc init = -0.5*bs (fp32) => acc = dot - 0.5*bs => d2 = qs - 2*acc.
// Gate: d2 <= g  <=>  acc >= h = 0.5*(qs - g).
// Gate-merge events (EV_MASK): each quad computes its EXACT pooled top-9
// (leader-keeps / follower-clears preserves element-disjointness across
// lanes — see round-5 bug note in the previous session). NEW this round:
// the two waves (bw=0/1) cover disjoint bank rows, so the event also pools
// cross-wave via sm_pool and publishes the EXACT block-level 9th (strictly
// tighter than the quad 9ths, still an upper bound of the true 9th => safe).
// The merged list is publish-only; t9 is never overwritten with it, so the
// per-wave disjointness invariant is untouched.
// Last seg-block per qgroup (done-counter + threadfence + agent-scope loads)
// folds the 32 sorted per-seg lists and writes the output.
// ---------------------------------------------------------------------------
__global__ __launch_bounds__(256, 3)
void knn_main(const __hip_bfloat16* __restrict__ bankbf,
              const __hip_bfloat16* __restrict__ featbf,
              const float* __restrict__ bsqn,
              const float* __restrict__ qsqp,
              int* __restrict__ thr_g,
              float* __restrict__ part,
              int* __restrict__ done,
              float* __restrict__ out) {
    __shared__ __align__(16) short sm_bt[2][16 * 512];   // 2 x 16 KB bank tile
    __shared__ __align__(16) float sm_pool[QB][K_NEI];   // 4.6 KB event/epilogue pool
    __shared__ int sm_last;

    const int tid  = threadIdx.x;
    const int lane = tid & 63;
    const int wv   = tid >> 6;
    const int qw   = wv & 1;        // query half of block
    const int bw   = wv >> 1;       // bank half of chunk
    // XCD swizzle: seg%8 == blockIdx%8
    const int s8  = blockIdx.x & 7;
    const int t_  = blockIdx.x >> 3;
    const int bq  = t_ & 31;
    const int seg = ((t_ >> 5) << 3) | s8;   // 0..31
    const int qbase  = bq * QB;
    const int cbase0 = seg * SEG_LEN;
    const int l15 = lane & 15, l4 = lane >> 4;

    // query fragments (B operand), cached in registers for the whole block
    bf16x8 qf[4][4];
    float qs4[4];
    int qglob[4], qloc[4];
#pragma unroll
    for (int qt = 0; qt < 4; ++qt) {
        int q = qbase + qw * 64 + qt * 16 + l15;
        qglob[qt] = q;
        qloc[qt]  = qw * 64 + qt * 16 + l15;
        qs4[qt]   = qsqp[q];
#pragma unroll
        for (int ks = 0; ks < 4; ++ks)
            qf[qt][ks] = *(const bf16x8*)(featbf + (size_t)q * D + ks * 32 + l4 * 8);
    }

    float t9[4][K_NEI];
    float g[4], lastpub[4];
#pragma unroll
    for (int qt = 0; qt < 4; ++qt) {
        g[qt] = FLT_MAX;
        lastpub[qt] = FLT_MAX;
#pragma unroll
        for (int j = 0; j < K_NEI; ++j) t9[qt][j] = FLT_MAX;
    }

    // prologue: stage chunk 0 into buffer 0 (4 regions of 1KB per wave)
#pragma unroll
    for (int i = 0; i < 4; ++i) {
        int rgn = wv * 4 + i;
        int bt = rgn >> 2, ks = rgn & 3;
        const __hip_bfloat16* gp =
            bankbf + (size_t)(cbase0 + bt * 16 + l15) * D + ks * 32 + l4 * 8;
        GL_LDS16(gp, &sm_bt[0][rgn * 512]);
    }
    // preload chunk-0 acc-init (-0.5*bs) into registers
    floatx4 ini[2];
#pragma unroll
    for (int bb = 0; bb < 2; ++bb)
        ini[bb] = *(const floatx4*)&bsqn[cbase0 + (bw * 2 + bb) * 16 + l4 * 4];

#pragma unroll 1
    for (int ch = 0; ch < CHUNKS; ++ch) {
        const int cur = ch & 1;
        __syncthreads();  // drains own vmcnt -> buf[cur] ready; buf[cur^1] free

        // issue next chunk's staging immediately (lands during this body)
        floatx4 nini[2] = {};
        if (ch + 1 < CHUNKS) {
            const int cb1 = cbase0 + (ch + 1) * BB;
#pragma unroll
            for (int i = 0; i < 4; ++i) {
                int rgn = wv * 4 + i;
                int bt = rgn >> 2, ks = rgn & 3;
                const __hip_bfloat16* gp =
                    bankbf + (size_t)(cb1 + bt * 16 + l15) * D + ks * 32 + l4 * 8;
                GL_LDS16(gp, &sm_bt[cur ^ 1][rgn * 512]);
            }
            // prefetch next chunk's acc-init (consumed next iteration)
#pragma unroll
            for (int bb = 0; bb < 2; ++bb)
                nini[bb] = *(const floatx4*)&bsqn[cb1 + (bw * 2 + bb) * 16 + l4 * 4];
        }
        // refresh gates from device-global thresholds (consumed after MFMA)
        int tg[4];
#pragma unroll
        for (int qt = 0; qt < 4; ++qt)
            tg[qt] = __hip_atomic_load(&thr_g[qglob[qt]], __ATOMIC_RELAXED,
                                       __HIP_MEMORY_SCOPE_AGENT);

        // acc init from prefetched registers (no load stall before MFMA)
        floatx4 acc[2][4];
#pragma unroll
        for (int bb = 0; bb < 2; ++bb)
#pragma unroll
            for (int qt = 0; qt < 4; ++qt) acc[bb][qt] = ini[bb];

        // MFMA: 2 bank-tiles x 4 query-tiles, K = 128 (4 ksteps of 32)
#pragma unroll
        for (int ks = 0; ks < 4; ++ks) {
            bf16x8 af[2];
#pragma unroll
            for (int bb = 0; bb < 2; ++bb)
                af[bb] = *(const bf16x8*)
                    &sm_bt[cur][((bw * 2 + bb) * 4 + ks) * 512 + lane * 8];
#pragma unroll
            for (int bb = 0; bb < 2; ++bb)
#pragma unroll
                for (int qt = 0; qt < 4; ++qt)
                    acc[bb][qt] = mfma16(af[bb], qf[qt][ks], acc[bb][qt]);
        }
        ini[0] = nini[0]; ini[1] = nini[1];

        // gates -> thresholds on raw acc (loosening guards transform rounding)
        float h[4];
#pragma unroll
        for (int qt = 0; qt < 4; ++qt) {
            g[qt] = fminf(g[qt], __int_as_float(tg[qt]));
            h[qt] = 0.5f * (qs4[qt] - g[qt] * 1.0000005f);
        }

        // selection: 1 reg-max + 1 v_cmp per 4 elements; rare insert path
#pragma unroll
        for (int bb = 0; bb < 2; ++bb) {
#pragma unroll
            for (int qt = 0; qt < 4; ++qt) {
                float a0 = acc[bb][qt][0], a1 = acc[bb][qt][1];
                float a2 = acc[bb][qt][2], a3 = acc[bb][qt][3];
                float mx = fmaxf(fmaxf(a0, a1), fmaxf(a2, a3));
                if (__ballot(mx >= h[qt])) {
#pragma unroll
                    for (int r = 0; r < 4; ++r) {
                        float a = acc[bb][qt][r];
                        if (a >= h[qt]) {
                            float d2 = fmaxf(fmaf(-2.f, a, qs4[qt]), 0.f);
                            if (d2 <= g[qt]) {
                                t9[qt][K_NEI - 1] = d2;
#pragma unroll
                                for (int s = K_NEI - 1; s > 0; --s)
                                    ce(t9[qt][s - 1], t9[qt][s]);
                                g[qt] = fminf(g[qt], t9[qt][K_NEI - 1]);
                            }
                        }
                    }
                }
            }
        }
        // gate-merge events: exact quad pool, then exact cross-wave (block)
        // pool via LDS; bw=1 publishes the block 9th. Leader keeps the quad
        // list, followers clear (disjointness). The cross-wave merged list is
        // publish-only.
        if ((EV_MASK >> ch) & 1) {
#pragma unroll
            for (int qt = 0; qt < 4; ++qt) {
                quad_merge(t9[qt]);
                g[qt] = fminf(g[qt], t9[qt][K_NEI - 1]);
            }
            if (bw == 0 && l4 == 0) {
#pragma unroll
                for (int qt = 0; qt < 4; ++qt)
#pragma unroll
                    for (int j = 0; j < K_NEI; ++j)
                        sm_pool[qloc[qt]][j] = t9[qt][j];
            }
            __syncthreads();
            if (bw == 1) {
#pragma unroll
                for (int qt = 0; qt < 4; ++qt) {
                    float mg[K_NEI], o[K_NEI];
#pragma unroll
                    for (int j = 0; j < K_NEI; ++j) {
                        mg[j] = t9[qt][j];
                        o[j]  = sm_pool[qloc[qt]][j];
                    }
                    merge9(mg, o);         // exact block 9th (disjoint rows)
                    float nth = mg[K_NEI - 1];
                    g[qt] = fminf(g[qt], nth);
                    if (l4 == 0 && nth < lastpub[qt]) {
                        atomicMin(&thr_g[qglob[qt]], __float_as_int(nth));
                        lastpub[qt] = nth;
                    }
                }
            }
            if (l4 != 0) {
                // followers: reset so lists stay element-disjoint
#pragma unroll
                for (int qt = 0; qt < 4; ++qt)
#pragma unroll
                    for (int j = 0; j < K_NEI; ++j) t9[qt][j] = FLT_MAX;
            }
        }
    }

    // ---- epilogue: pool quad (disjoint), then cross-wave (bw) via LDS -----
#pragma unroll
    for (int qt = 0; qt < 4; ++qt) quad_merge(t9[qt]);
    if (bw == 0 && l4 == 0) {
#pragma unroll
        for (int qt = 0; qt < 4; ++qt)
#pragma unroll
            for (int j = 0; j < K_NEI; ++j)
                sm_pool[qloc[qt]][j] = t9[qt][j];
    }
    __syncthreads();
    if (bw == 1 && l4 == 0) {
#pragma unroll
        for (int qt = 0; qt < 4; ++qt) {
            float o[K_NEI];
#pragma unroll
            for (int j = 0; j < K_NEI; ++j) o[j] = sm_pool[qloc[qt]][j];
            merge9(t9[qt], o);   // block-pooled sorted top-9 for this segment
            float* dst = part + ((size_t)(qbase + qloc[qt]) * SEGS + seg) * K_NEI;
#pragma unroll
            for (int j = 0; j < K_NEI; ++j) dst[j] = t9[qt][j];
        }
    }

    // ---- fused final: last seg-block of this qgroup folds 32 sorted lists --
    __threadfence();            // release our part writes device-wide
    __syncthreads();
    if (tid == 0)
        sm_last = (atomicAdd(&done[bq], 1) == SEGS - 1) ? 1 : 0;
    __syncthreads();
    if (sm_last && tid < QB) {
        int q = qbase + tid;
        const float* p = part + (size_t)q * SEGS * K_NEI;
        float R[K_NEI], nx[K_NEI];
#pragma unroll
        for (int j = 0; j < K_NEI; ++j)
            R[j] = __hip_atomic_load(p + j, __ATOMIC_RELAXED,
                                     __HIP_MEMORY_SCOPE_AGENT);
#pragma unroll
        for (int j = 0; j < K_NEI; ++j)
            nx[j] = __hip_atomic_load(p + K_NEI + j, __ATOMIC_RELAXED,
                                      __HIP_MEMORY_SCOPE_AGENT);
#pragma unroll 1
        for (int s = 1; s < SEGS; ++s) {
            float o[K_NEI];
#pragma unroll
            for (int j = 0; j < K_NEI; ++j) o[j] = nx[j];
            if (s + 1 < SEGS) {
#pragma unroll
                for (int j = 0; j < K_NEI; ++j)
                    nx[j] = __hip_atomic_load(p + (s + 1) * K_NEI + j,
                                              __ATOMIC_RELAXED,
                                              __HIP_MEMORY_SCOPE_AGENT);
            }
            merge9(R, o);
        }
        float sum = 0.f;
#pragma unroll
        for (int j = 0; j < K_NEI; ++j) sum += sqrtf(fmaxf(R[j], 0.f));
        out[q] = sum * (1.0f / 9.0f);
    }
}

// ---------------------------------------------------------------------------
extern "C" void kernel_launch(void* const* d_in, const int* in_sizes, int n_in,
                              void* d_out, int out_size, void* d_ws, size_t ws_size,
                              hipStream_t stream) {
    const float* feats = (const float*)d_in[0];   // [M, D]
    const float* bank  = (const float*)d_in[1];   // [N, D]

    char* w = (char*)d_ws;
    __hip_bfloat16* bankbf = (__hip_bfloat16*)w;                       // 16 MB
    __hip_bfloat16* featbf = (__hip_bfloat16*)(w + (size_t)N * D * 2); // 1 MB
    float* bsqn = (float*)(w + (size_t)(N + M) * D * 2);               // 256 KB
    float* qsqp = bsqn + N;                                            // 16 KB
    float* part = qsqp + M;                                            // 4.5 MB
    int*   thr_g = (int*)(part + (size_t)M * SEGS * K_NEI);            // 16 KB
    int*   done  = thr_g + M;                                          // 128 B
    float* out  = (float*)d_out;

    prep_kernel<<<(N + M) / 8, 256, 0, stream>>>(bank, feats, bankbf, featbf,
                                                 bsqn, qsqp, thr_g, done);
    knn_main<<<QGROUPS * SEGS, 256, 0, stream>>>(bankbf, featbf, bsqn, qsqp,
                                                 thr_g, part, done, out);
}

// Round 2
// 420.081 us; speedup vs baseline: 1.2093x; 1.2093x over previous
//
#include <hip/hip_runtime.h>
#include <hip/hip_bf16.h>
#include <float.h>

#define K_NEI 9
#define M 4096
#define N 65536
#define D 128
#define SEGS 8                  // one segment per XCD
#define SEG_LEN (N / SEGS)      // 8192 bank rows per segment
#define QB 32                   // queries per block (2 MFMA query-tiles)
#define QT 2                    // query tiles per wave
#define BB 64                   // bank rows per chunk (16 per wave)
#define CHUNKS (SEG_LEN / BB)   // 128
#define QGROUPS (M / QB)        // 128

typedef __bf16 bf16x8 __attribute__((ext_vector_type(8)));
typedef float floatx4 __attribute__((ext_vector_type(4)));

static __device__ inline floatx4 mfma16(bf16x8 a, bf16x8 b, floatx4 c) {
    return __builtin_amdgcn_mfma_f32_16x16x32_bf16(a, b, c, 0, 0, 0);
}

// ---- sorted-9 toolkit -----------------------------------------------------
static __device__ inline void ce(float& a, float& b) {
    float lo = fminf(a, b), hi = fmaxf(a, b); a = lo; b = hi;
}
// canonical optimal 25-CE / depth-7 sorting network for 9 (ascending)
static __device__ inline void sort9(float t[K_NEI]) {
    ce(t[0],t[3]); ce(t[1],t[7]); ce(t[2],t[5]); ce(t[4],t[8]);
    ce(t[0],t[7]); ce(t[2],t[4]); ce(t[3],t[8]); ce(t[5],t[6]);
    ce(t[0],t[2]); ce(t[1],t[3]); ce(t[4],t[5]); ce(t[7],t[8]);
    ce(t[1],t[4]); ce(t[3],t[6]); ce(t[5],t[7]);
    ce(t[0],t[1]); ce(t[2],t[4]); ce(t[3],t[5]); ce(t[6],t[8]);
    ce(t[2],t[3]); ce(t[4],t[5]); ce(t[6],t[7]);
    ce(t[1],t[2]); ce(t[3],t[4]); ce(t[5],t[6]);
}
// t, o sorted ascending -> t = sorted 9 smallest of union (bitonic min trick)
static __device__ inline void merge9(float t[K_NEI], const float o[K_NEI]) {
    float m[K_NEI];
#pragma unroll
    for (int i = 0; i < K_NEI; ++i) m[i] = fminf(t[i], o[K_NEI - 1 - i]);
    sort9(m);
#pragma unroll
    for (int i = 0; i < K_NEI; ++i) t[i] = m[i];
}
// pool the 4 partner lanes (lane ^16, ^32): all 4 end with identical exact
// top-9 of the quad's union. ONLY valid if the 4 lists are element-disjoint.
static __device__ inline void quad_merge(float t[K_NEI]) {
    float o[K_NEI];
#pragma unroll
    for (int i = 0; i < K_NEI; ++i) o[i] = __shfl_xor(t[i], 16, 64);
    merge9(t, o);
#pragma unroll
    for (int i = 0; i < K_NEI; ++i) o[i] = __shfl_xor(t[i], 32, 64);
    merge9(t, o);
}

// ---------------------------------------------------------------------------
// Kernel 1 (fused prep): fp32 -> bf16 convert + row norms for BOTH inputs,
// plus per-call init of thr_g (gates) and done (qgroup counters).
// Vectorized: 32 lanes/row, float4 loads, packed 4B bf16 stores.
// ---------------------------------------------------------------------------
static __device__ inline unsigned pack2bf(float a, float b) {
    __hip_bfloat16 x = __float2bfloat16(a), y = __float2bfloat16(b);
    unsigned short ux = *(unsigned short*)&x, uy = *(unsigned short*)&y;
    return (unsigned)ux | ((unsigned)uy << 16);
}

__global__ void prep_kernel(const float* __restrict__ bank,
                            const float* __restrict__ feats,
                            __hip_bfloat16* __restrict__ bankbf,
                            __hip_bfloat16* __restrict__ featbf,
                            float* __restrict__ bsqn,
                            float* __restrict__ qsq,
                            int* __restrict__ thr_g,
                            int* __restrict__ done) {
    int row = (int)((blockIdx.x * blockDim.x + threadIdx.x) >> 5);
    int l   = threadIdx.x & 31;
    if (row >= N + M) return;
    const float* src = (row < N) ? (bank + (size_t)row * D)
                                 : (feats + (size_t)(row - N) * D);
    __hip_bfloat16* dst = (row < N) ? (bankbf + (size_t)row * D)
                                    : (featbf + (size_t)(row - N) * D);
    float4 v = ((const float4*)src)[l];
    float s = v.x * v.x + v.y * v.y + v.z * v.z + v.w * v.w;
    uint2 p;
    p.x = pack2bf(v.x, v.y);
    p.y = pack2bf(v.z, v.w);
    ((uint2*)dst)[l] = p;
    // xor-reduce within the 32-lane group (offsets <32 never cross groups)
#pragma unroll
    for (int off = 16; off > 0; off >>= 1) s += __shfl_xor(s, off, 64);
    if (l == 0) {
        if (row < N) {
            bsqn[row] = -0.5f * s;
        } else {
            qsq[row - N] = s;
            thr_g[row - N] = 0x7f7f7f7f;   // 3.39e38f
        }
    }
    if (l == 1 && row >= N && row < N + QGROUPS) done[row - N] = 0;
}

// ---------------------------------------------------------------------------
// Kernel 2: barrier-free streaming MFMA + fused per-query top-9 + final merge.
//
// STRUCTURE (round-2 redesign): no LDS bank staging, no __syncthreads in the
// main loop. Each XCD's bank segment (2 MB bf16) is L2-resident (seg ==
// blockIdx&7 == XCD under round-robin dispatch), so bank A-fragments stream
// global->VGPR directly; queries stay in registers for the whole kernel.
// grid = 1024 blocks of 256 threads; ~120 VGPR -> 4 blocks/CU (16 waves/CU).
// Per chunk (64 rows, 16/wave): 8 MFMA -> issue next chunk's 4 loads + bsqn
// (latency hidden under selection) -> gated selection -> rare event.
//
// acc init = -0.5*bs (fp32) => acc = dot - 0.5*bs => d2 = qs - 2*acc.
// Gate: d2 <= g  <=>  acc >= h = 0.5*(qs - g).
// Gate refresh: thr_g loaded every 4th chunk, issued one chunk before
// consumption (stale gates are looser => always safe).
// Gate-merge events (ch = 3,7,15,31,63,95: same 64..1536-row coverage
// schedule as the 367us kernel): quad computes its EXACT pooled top-9;
// leader (l4==0) keeps the pooled list, followers reset to +INF so the four
// per-lane lists stay element-disjoint (round-5 bug invariant). Publish only
// on strict improvement over everything already known (nth < g_pre).
// Exactness is gate-independent: skipped elements satisfy d2 > g >= true 9th.
// Epilogue: quad pool -> cross-wave pool via small LDS -> part write; last
// seg-block per qgroup (done counter + fence + agent-scope loads) folds the
// 8 sorted per-seg lists and writes the output.
// ---------------------------------------------------------------------------
__global__ __launch_bounds__(256, 4)
void knn_main(const __hip_bfloat16* __restrict__ bankbf,
              const __hip_bfloat16* __restrict__ featbf,
              const float* __restrict__ bsqn,
              const float* __restrict__ qsqp,
              int* __restrict__ thr_g,
              float* __restrict__ part,
              int* __restrict__ done,
              float* __restrict__ out) {
    __shared__ __align__(16) float sm_pool[4][QB][K_NEI];  // 4.6 KB
    __shared__ int sm_last;

    const int tid  = threadIdx.x;
    const int lane = tid & 63;
    const int wv   = tid >> 6;
    const int l15  = lane & 15, l4 = lane >> 4;

    const int seg   = blockIdx.x & 7;     // == XCD id (L2-resident segment)
    const int bq    = blockIdx.x >> 3;    // 0..127
    const int qbase = bq * QB;
    const int sbase = seg * SEG_LEN;

    // query fragments (B operand) in registers for the whole kernel
    bf16x8 qf[QT][4];
    float qs[QT], g[QT];
    float t9[QT][K_NEI];
#pragma unroll
    for (int qt = 0; qt < QT; ++qt) {
        int q = qbase + qt * 16 + l15;
        qs[qt] = qsqp[q];
        g[qt]  = FLT_MAX;
#pragma unroll
        for (int ks = 0; ks < 4; ++ks)
            qf[qt][ks] = *(const bf16x8*)(featbf + (size_t)q * D + ks * 32 + l4 * 8);
#pragma unroll
        for (int j = 0; j < K_NEI; ++j) t9[qt][j] = FLT_MAX;
    }

    // per-wave bank base: row = sbase + wv*16 + l15, k-slice = l4*8
    const __hip_bfloat16* abase =
        bankbf + (size_t)(sbase + wv * 16 + l15) * D + l4 * 8;
    const int ibase = sbase + wv * 16 + l4 * 4;   // bsqn floatx4 index

    // prologue: chunk 0 fragments + acc-init
    bf16x8 af[4];
#pragma unroll
    for (int ks = 0; ks < 4; ++ks)
        af[ks] = *(const bf16x8*)(abase + ks * 32);
    floatx4 ini = *(const floatx4*)&bsqn[ibase];

    int tg0 = 0x7f7f7f7f, tg1 = 0x7f7f7f7f;

#pragma unroll 1
    for (int ch = 0; ch < CHUNKS; ++ch) {
        // ---- MFMA on current chunk (af loaded last iteration) ----
        floatx4 acc[QT];
#pragma unroll
        for (int qt = 0; qt < QT; ++qt) acc[qt] = ini;
#pragma unroll
        for (int ks = 0; ks < 4; ++ks)
#pragma unroll
            for (int qt = 0; qt < QT; ++qt)
                acc[qt] = mfma16(af[ks], qf[qt][ks], acc[qt]);

        // ---- issue next chunk's loads; latency hides under selection ----
        if (ch + 1 < CHUNKS) {
            const __hip_bfloat16* ap = abase + (size_t)(ch + 1) * (BB * D);
#pragma unroll
            for (int ks = 0; ks < 4; ++ks)
                af[ks] = *(const bf16x8*)(ap + ks * 32);
            ini = *(const floatx4*)&bsqn[ibase + (ch + 1) * BB];
        }

        // ---- gate refresh: issue every 4th chunk, consume next chunk ----
        if ((ch & 3) == 0) {
            tg0 = __hip_atomic_load(&thr_g[qbase + l15], __ATOMIC_RELAXED,
                                    __HIP_MEMORY_SCOPE_AGENT);
            tg1 = __hip_atomic_load(&thr_g[qbase + 16 + l15], __ATOMIC_RELAXED,
                                    __HIP_MEMORY_SCOPE_AGENT);
        } else if ((ch & 3) == 1) {
            g[0] = fminf(g[0], __int_as_float(tg0));
            g[1] = fminf(g[1], __int_as_float(tg1));
        }
        float h[QT];
#pragma unroll
        for (int qt = 0; qt < QT; ++qt)
            h[qt] = 0.5f * (qs[qt] - g[qt] * 1.0000005f);

        // ---- selection: 1 reg-max + 1 v_cmp per 4 elements; rare inserts ----
#pragma unroll
        for (int qt = 0; qt < QT; ++qt) {
            float a0 = acc[qt][0], a1 = acc[qt][1];
            float a2 = acc[qt][2], a3 = acc[qt][3];
            float mx = fmaxf(fmaxf(a0, a1), fmaxf(a2, a3));
            if (__ballot(mx >= h[qt])) {
#pragma unroll
                for (int r = 0; r < 4; ++r) {
                    float a = acc[qt][r];
                    if (a >= h[qt]) {
                        float d2 = fmaxf(fmaf(-2.f, a, qs[qt]), 0.f);
                        if (d2 <= g[qt]) {
                            t9[qt][K_NEI - 1] = d2;
#pragma unroll
                            for (int s = K_NEI - 1; s > 0; --s)
                                ce(t9[qt][s - 1], t9[qt][s]);
                            g[qt] = fminf(g[qt], t9[qt][K_NEI - 1]);
                        }
                    }
                }
            }
        }

        // ---- gate-merge events: coverage {64,128,256,512,1024,1536} rows ----
        if (ch == 3 || ch == 7 || ch == 15 || ch == 31 || ch == 63 || ch == 95) {
#pragma unroll
            for (int qt = 0; qt < QT; ++qt) {
                float gpre = g[qt];
                quad_merge(t9[qt]);
                float nth = t9[qt][K_NEI - 1];
                g[qt] = fminf(g[qt], nth);
                if (l4 == 0) {
                    if (nth < gpre)
                        atomicMin(&thr_g[qbase + qt * 16 + l15],
                                  __float_as_int(nth));
                } else {
                    // follower: reset so lists stay element-disjoint
#pragma unroll
                    for (int j = 0; j < K_NEI; ++j) t9[qt][j] = FLT_MAX;
                }
            }
        }
    }

    // ---- epilogue: quad pool (disjoint), then 4-wave pool via LDS ---------
#pragma unroll
    for (int qt = 0; qt < QT; ++qt) quad_merge(t9[qt]);
    if (l4 == 0) {
#pragma unroll
        for (int qt = 0; qt < QT; ++qt)
#pragma unroll
            for (int j = 0; j < K_NEI; ++j)
                sm_pool[wv][qt * 16 + l15][j] = t9[qt][j];
    }
    __syncthreads();
    if (tid < QB) {
        float R[K_NEI];
#pragma unroll
        for (int j = 0; j < K_NEI; ++j) R[j] = sm_pool[0][tid][j];
#pragma unroll
        for (int w = 1; w < 4; ++w) {
            float o[K_NEI];
#pragma unroll
            for (int j = 0; j < K_NEI; ++j) o[j] = sm_pool[w][tid][j];
            merge9(R, o);
        }
        float* dst = part + ((size_t)(qbase + tid) * SEGS + seg) * K_NEI;
#pragma unroll
        for (int j = 0; j < K_NEI; ++j) dst[j] = R[j];
    }

    // ---- fused final: last seg-block of this qgroup folds 8 sorted lists --
    __threadfence();            // release our part writes device-wide
    __syncthreads();
    if (tid == 0)
        sm_last = (atomicAdd(&done[bq], 1) == SEGS - 1) ? 1 : 0;
    __syncthreads();
    if (sm_last && tid < QB) {
        int q = qbase + tid;
        const float* p = part + (size_t)q * SEGS * K_NEI;
        float R[K_NEI], nx[K_NEI];
#pragma unroll
        for (int j = 0; j < K_NEI; ++j)
            R[j] = __hip_atomic_load(p + j, __ATOMIC_RELAXED,
                                     __HIP_MEMORY_SCOPE_AGENT);
#pragma unroll
        for (int j = 0; j < K_NEI; ++j)
            nx[j] = __hip_atomic_load(p + K_NEI + j, __ATOMIC_RELAXED,
                                      __HIP_MEMORY_SCOPE_AGENT);
#pragma unroll 1
        for (int s = 1; s < SEGS; ++s) {
            float o[K_NEI];
#pragma unroll
            for (int j = 0; j < K_NEI; ++j) o[j] = nx[j];
            if (s + 1 < SEGS) {
#pragma unroll
                for (int j = 0; j < K_NEI; ++j)
                    nx[j] = __hip_atomic_load(p + (s + 1) * K_NEI + j,
                                              __ATOMIC_RELAXED,
                                              __HIP_MEMORY_SCOPE_AGENT);
            }
            merge9(R, o);
        }
        float sum = 0.f;
#pragma unroll
        for (int j = 0; j < K_NEI; ++j) sum += sqrtf(fmaxf(R[j], 0.f));
        out[q] = sum * (1.0f / 9.0f);
    }
}

// ---------------------------------------------------------------------------
extern "C" void kernel_launch(void* const* d_in, const int* in_sizes, int n_in,
                              void* d_out, int out_size, void* d_ws, size_t ws_size,
                              hipStream_t stream) {
    const float* feats = (const float*)d_in[0];   // [M, D]
    const float* bank  = (const float*)d_in[1];   // [N, D]

    char* w = (char*)d_ws;
    __hip_bfloat16* bankbf = (__hip_bfloat16*)w;                       // 16 MB
    __hip_bfloat16* featbf = (__hip_bfloat16*)(w + (size_t)N * D * 2); // 1 MB
    float* bsqn = (float*)(w + (size_t)(N + M) * D * 2);               // 256 KB
    float* qsqp = bsqn + N;                                            // 16 KB
    float* part = qsqp + M;                                            // 1.2 MB
    int*   thr_g = (int*)(part + (size_t)M * SEGS * K_NEI);            // 16 KB
    int*   done  = thr_g + M;                                          // 512 B
    float* out  = (float*)d_out;

    prep_kernel<<<(N + M) / 8, 256, 0, stream>>>(bank, feats, bankbf, featbf,
                                                 bsqn, qsqp, thr_g, done);
    knn_main<<<QGROUPS * SEGS, 256, 0, stream>>>(bankbf, featbf, bsqn, qsqp,
                                                 thr_g, part, done, out);
}